// Round 6
// baseline (150.117 us; speedup 1.0000x reference)
//
#include <hip/hip_runtime.h>
#include <hip/hip_fp16.h>

#define HW 128
#define PLANE (HW * HW)

typedef __attribute__((ext_vector_type(8))) _Float16 f16x8;
typedef __attribute__((ext_vector_type(4))) float f32x4;

__device__ __forceinline__ unsigned short f2h(float f) {
  return __half_as_ushort(__float2half(f));
}

// XCD-aware bijective swizzle (nwg % 8 == 0): XCD k gets a contiguous chunk.
__device__ __forceinline__ void tile_from_bid_512(int bid, int& b, int& by, int& bx) {
  int wg = (bid & 7) * 64 + (bid >> 3);
  b = wg >> 6;
  int t = wg & 63;
  by = (t >> 3) << 4;
  bx = (t & 7) << 4;
}

// ---------------- fused weight packing (all three) ----------------
// w1: [64][128][3][3] -> fp16 [(k>>3)*64+n][k&7], k=tap*128+ic   (73728 elems)
// w2: [18][64][3][3]  -> fp16 [(k>>3)*32+n][k&7], k=tap*64+ic, N pad 32 (18432)
// wd: [64][64][3][3]  -> fp16 [(k>>3)*64+n][k&7], k=tap*64+ic    (36864)
__global__ __launch_bounds__(256) void pack_all_kernel(
    const float* __restrict__ w1, const float* __restrict__ w2,
    const float* __restrict__ wd, unsigned short* __restrict__ w1p,
    unsigned short* __restrict__ w2p, unsigned short* __restrict__ wdp) {
  int idx = blockIdx.x * 256 + threadIdx.x;
  if (idx < 73728) {
    int k = idx >> 6, n = idx & 63;
    int tap = k >> 7, ic = k & 127;
    w1p[((k >> 3) * 64 + n) * 8 + (k & 7)] = f2h(w1[(n * 128 + ic) * 9 + tap]);
  } else if (idx < 73728 + 18432) {
    int i = idx - 73728;
    int k = i >> 5, n = i & 31;
    int tap = k >> 6, ic = k & 63;
    float v = (n < 18) ? w2[(n * 64 + ic) * 9 + tap] : 0.f;
    w2p[((k >> 3) * 32 + n) * 8 + (k & 7)] = f2h(v);
  } else if (idx < 73728 + 18432 + 36864) {
    int i = idx - 73728 - 18432;
    int k = i >> 6, n = i & 63;
    int tap = k >> 6, ic = k & 63;
    wdp[((k >> 3) * 64 + n) * 8 + (k & 7)] = f2h(wd[(n * 64 + ic) * 9 + tap]);
  }
}

// ---------------- ref,tgt NCHW fp32 -> NHWC fp16: xref [b][y][x][64], xtgt [b][y][x][64] ----------------
__global__ __launch_bounds__(256) void to_nhwc_kernel(
    const float* __restrict__ ref, const float* __restrict__ tgt,
    unsigned short* __restrict__ xref, unsigned short* __restrict__ xtgt) {
  __shared__ unsigned short lds[32][136];
  const int b = blockIdx.z, y = blockIdx.y, x0 = blockIdx.x * 32;
  for (int idx = threadIdx.x; idx < 4096; idx += 256) {
    int ic = idx >> 5, px = idx & 31;
    const float* src = (ic < 64) ? ref : tgt;
    lds[px][ic] = f2h(src[(b * 64 + (ic & 63)) * PLANE + y * HW + x0 + px]);
  }
  __syncthreads();
  for (int idx = threadIdx.x; idx < 512; idx += 256) {
    int px = idx >> 4, g = idx & 15;
    uint4 v = *(const uint4*)&lds[px][g * 8];
    size_t base = ((size_t)(b * HW + y) * HW + x0 + px) * 64;
    if (g < 8)
      *(uint4*)(xref + base + g * 8) = v;
    else
      *(uint4*)(xtgt + base + (g - 8) * 8) = v;
  }
}

// ---------------- conv1 via fp16 MFMA: (xref,xtgt) NHWC -> hmid fp16 NHWC (+bias, leaky) ----------------
__global__ __launch_bounds__(512) void conv1_mfma_kernel(
    const unsigned short* __restrict__ xref, const unsigned short* __restrict__ xtgt,
    const unsigned short* __restrict__ w1p, const float* __restrict__ b1,
    unsigned short* __restrict__ hm) {
  __shared__ unsigned short tileH[324 * 64];  // 41472 B, XOR-swizzled rows
  int b, by, bx;
  tile_from_bid_512(blockIdx.x, b, by, bx);
  const int tid = threadIdx.x, lane = tid & 63, w = tid >> 6;
  const int l15 = lane & 15, lg = lane >> 4;

  f32x4 acc[4][2];
#pragma unroll
  for (int mf = 0; mf < 4; ++mf)
#pragma unroll
    for (int q = 0; q < 2; ++q) acc[mf][q] = (f32x4){0.f, 0.f, 0.f, 0.f};

  for (int c = 0; c < 2; ++c) {
    const unsigned short* src = c ? xtgt : xref;
    __syncthreads();
    for (int i = tid; i < 2592; i += 512) {
      int pos = i >> 3, g = i & 7;
      int yy = pos / 18, xx = pos - yy * 18;
      int gy = by + yy - 1, gx = bx + xx - 1;
      uint4 v = make_uint4(0u, 0u, 0u, 0u);
      if ((unsigned)gy < 128u && (unsigned)gx < 128u)
        v = *(const uint4*)(src + ((size_t)(b * HW + gy) * HW + gx) * 64 + g * 8);
      *(uint4*)(tileH + pos * 64 + ((g * 8) ^ ((pos & 7) << 3))) = v;
    }
    __syncthreads();

#pragma unroll
    for (int tap = 0; tap < 9; ++tap) {
      const int ty = tap / 3, tx = tap - ty * 3;
#pragma unroll
      for (int ks = 0; ks < 2; ++ks) {
        f16x8 ap[2];
#pragma unroll
        for (int q = 0; q < 2; ++q) {
          int pos = (w * 2 + q + ty) * 18 + l15 + tx;
          ap[q] = *(const f16x8*)(tileH + pos * 64 + ((ks * 32 + lg * 8) ^ ((pos & 7) << 3)));
        }
        const int kb = tap * 16 + c * 8 + ks * 4 + lg;
        f16x8 aw[4];
#pragma unroll
        for (int mf = 0; mf < 4; ++mf)
          aw[mf] = *(const f16x8*)(w1p + (kb * 64 + mf * 16 + l15) * 8);
#pragma unroll
        for (int mf = 0; mf < 4; ++mf)
#pragma unroll
          for (int q = 0; q < 2; ++q)
            acc[mf][q] = __builtin_amdgcn_mfma_f32_16x16x32_f16(aw[mf], ap[q], acc[mf][q], 0, 0, 0);
      }
    }
  }

#pragma unroll
  for (int mf = 0; mf < 4; ++mf) {
    const float4 bv = ((const float4*)b1)[mf * 4 + lg];
#pragma unroll
    for (int q = 0; q < 2; ++q) {
      const int y = by + w * 2 + q;
      float v0 = acc[mf][q][0] + bv.x;
      float v1 = acc[mf][q][1] + bv.y;
      float v2 = acc[mf][q][2] + bv.z;
      float v3 = acc[mf][q][3] + bv.w;
      v0 = (v0 >= 0.f) ? v0 : 0.1f * v0;
      v1 = (v1 >= 0.f) ? v1 : 0.1f * v1;
      v2 = (v2 >= 0.f) ? v2 : 0.1f * v2;
      v3 = (v3 >= 0.f) ? v3 : 0.1f * v3;
      ushort4 s;
      s.x = f2h(v0); s.y = f2h(v1); s.z = f2h(v2); s.w = f2h(v3);
      *(ushort4*)(hm + ((size_t)(b * HW + y) * HW + bx + l15) * 64 + mf * 16 + lg * 4) = s;
    }
  }
}

// ---------------- conv2 via fp16 MFMA: hmid NHWC -> offsets fp32 [b][kk][y][x]{dy,dx} ----------------
__global__ __launch_bounds__(512) void conv2_mfma_kernel(
    const unsigned short* __restrict__ hm, const unsigned short* __restrict__ w2p,
    const float* __restrict__ b2, float* __restrict__ offsG) {
  __shared__ unsigned short tileH[324 * 64];  // 41472 B
  int b, by, bx;
  tile_from_bid_512(blockIdx.x, b, by, bx);
  const int tid = threadIdx.x, lane = tid & 63, w = tid >> 6;
  const int l15 = lane & 15, lg = lane >> 4;

  for (int i = tid; i < 2592; i += 512) {
    int pos = i >> 3, g = i & 7;
    int yy = pos / 18, xx = pos - yy * 18;
    int gy = by + yy - 1, gx = bx + xx - 1;
    uint4 v = make_uint4(0u, 0u, 0u, 0u);
    if ((unsigned)gy < 128u && (unsigned)gx < 128u)
      v = *(const uint4*)(hm + ((size_t)(b * HW + gy) * HW + gx) * 64 + g * 8);
    *(uint4*)(tileH + pos * 64 + ((g * 8) ^ ((pos & 7) << 3))) = v;
  }
  __syncthreads();

  f32x4 acc2[2][2];
#pragma unroll
  for (int q = 0; q < 2; ++q)
#pragma unroll
    for (int nf = 0; nf < 2; ++nf) acc2[q][nf] = (f32x4){0.f, 0.f, 0.f, 0.f};

#pragma unroll
  for (int tap = 0; tap < 9; ++tap) {
    const int ty = tap / 3, tx = tap - ty * 3;
#pragma unroll
    for (int ks = 0; ks < 2; ++ks) {
      f16x8 ap[2];
#pragma unroll
      for (int q = 0; q < 2; ++q) {
        int pos = (w * 2 + q + ty) * 18 + l15 + tx;
        ap[q] = *(const f16x8*)(tileH + pos * 64 + ((ks * 32 + lg * 8) ^ ((pos & 7) << 3)));
      }
      const int kb = tap * 8 + ks * 4 + lg;
      f16x8 bw[2];
#pragma unroll
      for (int nf = 0; nf < 2; ++nf)
        bw[nf] = *(const f16x8*)(w2p + (kb * 32 + nf * 16 + l15) * 8);
#pragma unroll
      for (int q = 0; q < 2; ++q)
#pragma unroll
        for (int nf = 0; nf < 2; ++nf)
          acc2[q][nf] = __builtin_amdgcn_mfma_f32_16x16x32_f16(ap[q], bw[nf], acc2[q][nf], 0, 0, 0);
    }
  }

#pragma unroll
  for (int nf = 0; nf < 2; ++nf) {
    const int oc = nf * 16 + l15;
    if (oc < 18) {
      const float bias = b2[oc];
      const int kk = oc >> 1, comp = oc & 1;
#pragma unroll
      for (int q = 0; q < 2; ++q) {
        const int y = by + w * 2 + q;
#pragma unroll
        for (int reg = 0; reg < 4; ++reg) {
          const int x = bx + lg * 4 + reg;
          offsG[(((size_t)(b * 9 + kk) * PLANE + y * HW + x) << 1) + comp] =
              acc2[q][nf][reg] + bias;
        }
      }
    }
  }
}

__device__ __forceinline__ uint4 blend4(uint4 a, uint4 b, uint4 c, uint4 d,
                                        __half2 h00, __half2 h01, __half2 h10, __half2 h11) {
  union U { uint4 u; __half2 h[4]; };
  U A, B, C, D, R;
  A.u = a; B.u = b; C.u = c; D.u = d;
#pragma unroll
  for (int i = 0; i < 4; ++i)
    R.h[i] = __hfma2(D.h[i], h11, __hfma2(C.h[i], h10, __hfma2(B.h[i], h01, __hmul2(A.h[i], h00))));
  return R.u;
}

// ---------------- deformable conv: lane-local gather -> MFMA A-frags, no LDS ----------------
// Grid 2048 x 256 thr = 8192 waves (1 per output row-strip): wave handles 1 row x 16 px
// x 64 oc. Lane (l15,lg): pixel x=bx+l15, ic chunk lg*8. Offsets double-buffered one
// tap ahead. VGPR capped at 64 (launch_bounds min 8 waves/EU) for full occupancy.
__global__ __launch_bounds__(256, 8) void deform_kernel(
    const unsigned short* __restrict__ xtgt, const float* __restrict__ offsG,
    const unsigned short* __restrict__ wdp, float* __restrict__ out) {
  const int bid = blockIdx.x;
  const int wg = (bid & 7) * 256 + (bid >> 3);  // bijective, 2048 % 8 == 0
  const int b = wg >> 8;
  const int t = wg & 255;
  const int by = (t >> 3) << 2, bx = (t & 7) << 4;
  const int tid = threadIdx.x, lane = tid & 63, w = tid >> 6;
  const int l15 = lane & 15, lg = lane >> 4;
  const int x = bx + l15, y = by + w;

  f32x4 acc[4];
#pragma unroll
  for (int nf = 0; nf < 4; ++nf) acc[nf] = (f32x4){0.f, 0.f, 0.f, 0.f};

  const unsigned short* tb = xtgt + (size_t)b * PLANE * 64;
  const float2* ob = (const float2*)offsG + (size_t)(b * 9) * PLANE + y * HW + x;

  float2 onx = ob[0];
  for (int kk = 0; kk < 9; ++kk) {
    const float2 o2 = onx;
    if (kk < 8) onx = ob[(size_t)(kk + 1) * PLANE];  // prefetch next tap's offsets
    const int kdy = kk / 3 - 1, kdx = kk - (kk / 3) * 3 - 1;
    float ys = (float)(y + kdy) + o2.x;
    float xs = (float)(x + kdx) + o2.y;
    float y0f = floorf(ys), x0f = floorf(xs);
    float wy = ys - y0f, wx = xs - x0f;
    int y0 = (int)y0f, x0i = (int)x0f;
    int y1 = y0 + 1, x1 = x0i + 1;
    float vy0 = (y0 >= 0 && y0 < HW) ? 1.f : 0.f;
    float vy1 = (y1 >= 0 && y1 < HW) ? 1.f : 0.f;
    float vx0 = (x0i >= 0 && x0i < HW) ? 1.f : 0.f;
    float vx1 = (x1 >= 0 && x1 < HW) ? 1.f : 0.f;
    int y0c = min(max(y0, 0), HW - 1), y1c = min(max(y1, 0), HW - 1);
    int x0c = min(max(x0i, 0), HW - 1), x1c = min(max(x1, 0), HW - 1);
    __half2 h00 = __float2half2_rn((1.f - wy) * (1.f - wx) * vy0 * vx0);
    __half2 h01 = __float2half2_rn((1.f - wy) * wx * vy0 * vx1);
    __half2 h10 = __float2half2_rn(wy * (1.f - wx) * vy1 * vx0);
    __half2 h11 = __float2half2_rn(wy * wx * vy1 * vx1);
    const unsigned short* p00 = tb + (y0c * HW + x0c) * 64 + lg * 8;
    const unsigned short* p01 = tb + (y0c * HW + x1c) * 64 + lg * 8;
    const unsigned short* p10 = tb + (y1c * HW + x0c) * 64 + lg * 8;
    const unsigned short* p11 = tb + (y1c * HW + x1c) * 64 + lg * 8;

#pragma unroll
    for (int ks = 0; ks < 2; ++ks) {
      uint4 av = *(const uint4*)(p00 + ks * 32);
      uint4 bv = *(const uint4*)(p01 + ks * 32);
      uint4 cv = *(const uint4*)(p10 + ks * 32);
      uint4 dv = *(const uint4*)(p11 + ks * 32);
      uint4 r = blend4(av, bv, cv, dv, h00, h01, h10, h11);
      f16x8 af = *(const f16x8*)&r;
      const int kb = kk * 8 + ks * 4 + lg;
#pragma unroll
      for (int nf = 0; nf < 4; ++nf) {
        f16x8 bw = *(const f16x8*)(wdp + (kb * 64 + nf * 16 + l15) * 8);
        acc[nf] = __builtin_amdgcn_mfma_f32_16x16x32_f16(af, bw, acc[nf], 0, 0, 0);
      }
    }
  }

  const int px0 = bx + lg * 4;
#pragma unroll
  for (int nf = 0; nf < 4; ++nf) {
    const int oc = nf * 16 + l15;
    float4 o;
    o.x = acc[nf][0];
    o.y = acc[nf][1];
    o.z = acc[nf][2];
    o.w = acc[nf][3];
    *(float4*)(out + (size_t)(b * 64 + oc) * PLANE + y * HW + px0) = o;
  }
}

extern "C" void kernel_launch(void* const* d_in, const int* in_sizes, int n_in,
                              void* d_out, int out_size, void* d_ws, size_t ws_size,
                              hipStream_t stream) {
  const float* ref = (const float*)d_in[0];
  const float* tgt = (const float*)d_in[1];
  const float* w1  = (const float*)d_in[2];
  const float* b1  = (const float*)d_in[3];
  const float* w2  = (const float*)d_in[4];
  const float* b2  = (const float*)d_in[5];
  const float* wd  = (const float*)d_in[6];

  // xref (fp16 NHWC, 16.8 MB) lives in d_out: dead before deform overwrites d_out.
  unsigned short* xref = (unsigned short*)d_out;
  float* out = (float*)d_out;

  char* ws = (char*)d_ws;
  unsigned short* xtgt  = (unsigned short*)ws;                   // 16777216 B
  unsigned short* hmid  = (unsigned short*)(ws + 16777216);      // 16777216 B
  float*          offsG = (float*)(ws + 33554432);               // 9437184 B
  unsigned short* w1p   = (unsigned short*)(ws + 42991616);      // 147456 B
  unsigned short* w2p   = (unsigned short*)(ws + 43139072);      // 36864 B
  unsigned short* wdp   = (unsigned short*)(ws + 43175936);      // 73728 B; end = 43249664

  pack_all_kernel<<<504, 256, 0, stream>>>(w1, w2, wd, w1p, w2p, wdp);

  to_nhwc_kernel<<<dim3(4, 128, 8), 256, 0, stream>>>(ref, tgt, xref, xtgt);

  conv1_mfma_kernel<<<512, 512, 0, stream>>>(xref, xtgt, w1p, b1, hmid);
  conv2_mfma_kernel<<<512, 512, 0, stream>>>(hmid, w2p, b2, offsG);
  deform_kernel<<<2048, 256, 0, stream>>>(xtgt, offsG, wdp, out);
}

// Round 7
// 99.990 us; speedup vs baseline: 1.5013x; 1.5013x over previous
//
#include <hip/hip_runtime.h>
#include <hip/hip_fp16.h>

#define HW 128
#define PLANE (HW * HW)

typedef __attribute__((ext_vector_type(8))) _Float16 f16x8;
typedef __attribute__((ext_vector_type(4))) float f32x4;

__device__ __forceinline__ unsigned short f2h(float f) {
  return __half_as_ushort(__float2half(f));
}

// XCD-aware bijective swizzle (nwg % 8 == 0): XCD k gets a contiguous chunk.
__device__ __forceinline__ void tile_from_bid_512(int bid, int& b, int& by, int& bx) {
  int wg = (bid & 7) * 64 + (bid >> 3);
  b = wg >> 6;
  int t = wg & 63;
  by = (t >> 3) << 4;
  bx = (t & 7) << 4;
}

// ---------------- fused weight packing (all three) ----------------
__global__ __launch_bounds__(256) void pack_all_kernel(
    const float* __restrict__ w1, const float* __restrict__ w2,
    const float* __restrict__ wd, unsigned short* __restrict__ w1p,
    unsigned short* __restrict__ w2p, unsigned short* __restrict__ wdp) {
  int idx = blockIdx.x * 256 + threadIdx.x;
  if (idx < 73728) {
    int k = idx >> 6, n = idx & 63;
    int tap = k >> 7, ic = k & 127;
    w1p[((k >> 3) * 64 + n) * 8 + (k & 7)] = f2h(w1[(n * 128 + ic) * 9 + tap]);
  } else if (idx < 73728 + 18432) {
    int i = idx - 73728;
    int k = i >> 5, n = i & 31;
    int tap = k >> 6, ic = k & 63;
    float v = (n < 18) ? w2[(n * 64 + ic) * 9 + tap] : 0.f;
    w2p[((k >> 3) * 32 + n) * 8 + (k & 7)] = f2h(v);
  } else if (idx < 73728 + 18432 + 36864) {
    int i = idx - 73728 - 18432;
    int k = i >> 6, n = i & 63;
    int tap = k >> 6, ic = k & 63;
    wdp[((k >> 3) * 64 + n) * 8 + (k & 7)] = f2h(wd[(n * 64 + ic) * 9 + tap]);
  }
}

// ---------------- ref,tgt NCHW fp32 -> NHWC fp16 ----------------
__global__ __launch_bounds__(256) void to_nhwc_kernel(
    const float* __restrict__ ref, const float* __restrict__ tgt,
    unsigned short* __restrict__ xref, unsigned short* __restrict__ xtgt) {
  __shared__ unsigned short lds[32][136];
  const int b = blockIdx.z, y = blockIdx.y, x0 = blockIdx.x * 32;
  for (int idx = threadIdx.x; idx < 4096; idx += 256) {
    int ic = idx >> 5, px = idx & 31;
    const float* src = (ic < 64) ? ref : tgt;
    lds[px][ic] = f2h(src[(b * 64 + (ic & 63)) * PLANE + y * HW + x0 + px]);
  }
  __syncthreads();
  for (int idx = threadIdx.x; idx < 512; idx += 256) {
    int px = idx >> 4, g = idx & 15;
    uint4 v = *(const uint4*)&lds[px][g * 8];
    size_t base = ((size_t)(b * HW + y) * HW + x0 + px) * 64;
    if (g < 8)
      *(uint4*)(xref + base + g * 8) = v;
    else
      *(uint4*)(xtgt + base + (g - 8) * 8) = v;
  }
}

// ---------------- conv1 via fp16 MFMA ----------------
__global__ __launch_bounds__(512) void conv1_mfma_kernel(
    const unsigned short* __restrict__ xref, const unsigned short* __restrict__ xtgt,
    const unsigned short* __restrict__ w1p, const float* __restrict__ b1,
    unsigned short* __restrict__ hm) {
  __shared__ unsigned short tileH[324 * 64];
  int b, by, bx;
  tile_from_bid_512(blockIdx.x, b, by, bx);
  const int tid = threadIdx.x, lane = tid & 63, w = tid >> 6;
  const int l15 = lane & 15, lg = lane >> 4;

  f32x4 acc[4][2];
#pragma unroll
  for (int mf = 0; mf < 4; ++mf)
#pragma unroll
    for (int q = 0; q < 2; ++q) acc[mf][q] = (f32x4){0.f, 0.f, 0.f, 0.f};

  for (int c = 0; c < 2; ++c) {
    const unsigned short* src = c ? xtgt : xref;
    __syncthreads();
    for (int i = tid; i < 2592; i += 512) {
      int pos = i >> 3, g = i & 7;
      int yy = pos / 18, xx = pos - yy * 18;
      int gy = by + yy - 1, gx = bx + xx - 1;
      uint4 v = make_uint4(0u, 0u, 0u, 0u);
      if ((unsigned)gy < 128u && (unsigned)gx < 128u)
        v = *(const uint4*)(src + ((size_t)(b * HW + gy) * HW + gx) * 64 + g * 8);
      *(uint4*)(tileH + pos * 64 + ((g * 8) ^ ((pos & 7) << 3))) = v;
    }
    __syncthreads();

#pragma unroll
    for (int tap = 0; tap < 9; ++tap) {
      const int ty = tap / 3, tx = tap - ty * 3;
#pragma unroll
      for (int ks = 0; ks < 2; ++ks) {
        f16x8 ap[2];
#pragma unroll
        for (int q = 0; q < 2; ++q) {
          int pos = (w * 2 + q + ty) * 18 + l15 + tx;
          ap[q] = *(const f16x8*)(tileH + pos * 64 + ((ks * 32 + lg * 8) ^ ((pos & 7) << 3)));
        }
        const int kb = tap * 16 + c * 8 + ks * 4 + lg;
        f16x8 aw[4];
#pragma unroll
        for (int mf = 0; mf < 4; ++mf)
          aw[mf] = *(const f16x8*)(w1p + (kb * 64 + mf * 16 + l15) * 8);
#pragma unroll
        for (int mf = 0; mf < 4; ++mf)
#pragma unroll
          for (int q = 0; q < 2; ++q)
            acc[mf][q] = __builtin_amdgcn_mfma_f32_16x16x32_f16(aw[mf], ap[q], acc[mf][q], 0, 0, 0);
      }
    }
  }

#pragma unroll
  for (int mf = 0; mf < 4; ++mf) {
    const float4 bv = ((const float4*)b1)[mf * 4 + lg];
#pragma unroll
    for (int q = 0; q < 2; ++q) {
      const int y = by + w * 2 + q;
      float v0 = acc[mf][q][0] + bv.x;
      float v1 = acc[mf][q][1] + bv.y;
      float v2 = acc[mf][q][2] + bv.z;
      float v3 = acc[mf][q][3] + bv.w;
      v0 = (v0 >= 0.f) ? v0 : 0.1f * v0;
      v1 = (v1 >= 0.f) ? v1 : 0.1f * v1;
      v2 = (v2 >= 0.f) ? v2 : 0.1f * v2;
      v3 = (v3 >= 0.f) ? v3 : 0.1f * v3;
      ushort4 s;
      s.x = f2h(v0); s.y = f2h(v1); s.z = f2h(v2); s.w = f2h(v3);
      *(ushort4*)(hm + ((size_t)(b * HW + y) * HW + bx + l15) * 64 + mf * 16 + lg * 4) = s;
    }
  }
}

// ---------------- conv2 via fp16 MFMA: hmid NHWC -> offsets fp32 [b][kk][y][x]{dy,dx} ----------------
__global__ __launch_bounds__(512) void conv2_mfma_kernel(
    const unsigned short* __restrict__ hm, const unsigned short* __restrict__ w2p,
    const float* __restrict__ b2, float* __restrict__ offsG) {
  __shared__ unsigned short tileH[324 * 64];
  int b, by, bx;
  tile_from_bid_512(blockIdx.x, b, by, bx);
  const int tid = threadIdx.x, lane = tid & 63, w = tid >> 6;
  const int l15 = lane & 15, lg = lane >> 4;

  for (int i = tid; i < 2592; i += 512) {
    int pos = i >> 3, g = i & 7;
    int yy = pos / 18, xx = pos - yy * 18;
    int gy = by + yy - 1, gx = bx + xx - 1;
    uint4 v = make_uint4(0u, 0u, 0u, 0u);
    if ((unsigned)gy < 128u && (unsigned)gx < 128u)
      v = *(const uint4*)(hm + ((size_t)(b * HW + gy) * HW + gx) * 64 + g * 8);
    *(uint4*)(tileH + pos * 64 + ((g * 8) ^ ((pos & 7) << 3))) = v;
  }
  __syncthreads();

  f32x4 acc2[2][2];
#pragma unroll
  for (int q = 0; q < 2; ++q)
#pragma unroll
    for (int nf = 0; nf < 2; ++nf) acc2[q][nf] = (f32x4){0.f, 0.f, 0.f, 0.f};

#pragma unroll
  for (int tap = 0; tap < 9; ++tap) {
    const int ty = tap / 3, tx = tap - ty * 3;
#pragma unroll
    for (int ks = 0; ks < 2; ++ks) {
      f16x8 ap[2];
#pragma unroll
      for (int q = 0; q < 2; ++q) {
        int pos = (w * 2 + q + ty) * 18 + l15 + tx;
        ap[q] = *(const f16x8*)(tileH + pos * 64 + ((ks * 32 + lg * 8) ^ ((pos & 7) << 3)));
      }
      const int kb = tap * 8 + ks * 4 + lg;
      f16x8 bw[2];
#pragma unroll
      for (int nf = 0; nf < 2; ++nf)
        bw[nf] = *(const f16x8*)(w2p + (kb * 32 + nf * 16 + l15) * 8);
#pragma unroll
      for (int q = 0; q < 2; ++q)
#pragma unroll
        for (int nf = 0; nf < 2; ++nf)
          acc2[q][nf] = __builtin_amdgcn_mfma_f32_16x16x32_f16(ap[q], bw[nf], acc2[q][nf], 0, 0, 0);
    }
  }

#pragma unroll
  for (int nf = 0; nf < 2; ++nf) {
    const int oc = nf * 16 + l15;
    if (oc < 18) {
      const float bias = b2[oc];
      const int kk = oc >> 1, comp = oc & 1;
#pragma unroll
      for (int q = 0; q < 2; ++q) {
        const int y = by + w * 2 + q;
#pragma unroll
        for (int reg = 0; reg < 4; ++reg) {
          const int x = bx + lg * 4 + reg;
          offsG[(((size_t)(b * 9 + kk) * PLANE + y * HW + x) << 1) + comp] =
              acc2[q][nf][reg] + bias;
        }
      }
    }
  }
}

__device__ __forceinline__ uint4 blend4(uint4 a, uint4 b, uint4 c, uint4 d,
                                        __half2 h00, __half2 h01, __half2 h10, __half2 h11) {
  union U { uint4 u; __half2 h[4]; };
  U A, B, C, D, R;
  A.u = a; B.u = b; C.u = c; D.u = d;
#pragma unroll
  for (int i = 0; i < 4; ++i)
    R.h[i] = __hfma2(D.h[i], h11, __hfma2(C.h[i], h10, __hfma2(B.h[i], h01, __hmul2(A.h[i], h00))));
  return R.u;
}

// ---------------- deformable conv: LDS-staged window gather + fp16 MFMA ----------------
// 512 thr = 8 waves per 16x16 tile; wave w owns rows by+w*2+{0,1}.
// Stage 20x20 px halo (record padded 128->144 B: stride 36 banks -> <=2-way conflict)
// once per block; bilinear corners read via ds_read_b128. Offsets are unbounded ->
// rare exec-masked global fallback when a corner leaves the window.
__global__ __launch_bounds__(512, 4) void deform_kernel(
    const unsigned short* __restrict__ xtgt, const float* __restrict__ offsG,
    const unsigned short* __restrict__ wdp, float* __restrict__ out) {
  __shared__ __align__(16) unsigned short win[400 * 72];  // 57600 B
  int b, by, bx;
  tile_from_bid_512(blockIdx.x, b, by, bx);
  const int tid = threadIdx.x, lane = tid & 63, w = tid >> 6;
  const int l15 = lane & 15, lg = lane >> 4;
  const int x = bx + l15;

  const unsigned short* tb = xtgt + (size_t)b * PLANE * 64;

  // ---- stage 20x20 halo (rows by-2..by+17, cols bx-2..bx+17) ----
  for (int i = tid; i < 3200; i += 512) {
    int rec = i >> 3, g = i & 7;
    int wy = rec / 20, wx = rec - wy * 20;
    int gy = by - 2 + wy, gx = bx - 2 + wx;
    uint4 v = make_uint4(0u, 0u, 0u, 0u);
    if ((unsigned)gy < 128u && (unsigned)gx < 128u)
      v = *(const uint4*)(tb + ((size_t)gy * HW + gx) * 64 + g * 8);
    *(uint4*)(win + rec * 72 + g * 8) = v;
  }
  __syncthreads();

  f32x4 acc[2][4];
#pragma unroll
  for (int q = 0; q < 2; ++q)
#pragma unroll
    for (int nf = 0; nf < 4; ++nf) acc[q][nf] = (f32x4){0.f, 0.f, 0.f, 0.f};

  const float2* ob = (const float2*)offsG + (size_t)(b * 9) * PLANE + (by + w * 2) * HW + x;

  for (int kk = 0; kk < 9; ++kk) {
    const int kdy = kk / 3 - 1, kdx = kk - (kk / 3) * 3 - 1;
    f16x8 af[2][2];
#pragma unroll
    for (int q = 0; q < 2; ++q) {
      const int y = by + w * 2 + q;
      const float2 o2 = ob[(size_t)kk * PLANE + q * HW];
      float ys = (float)(y + kdy) + o2.x;
      float xs = (float)(x + kdx) + o2.y;
      float y0f = floorf(ys), x0f = floorf(xs);
      float wy = ys - y0f, wx = xs - x0f;
      int y0 = (int)y0f, x0i = (int)x0f;
      int y1 = y0 + 1, x1 = x0i + 1;
      float vy0 = (y0 >= 0 && y0 < HW) ? 1.f : 0.f;
      float vy1 = (y1 >= 0 && y1 < HW) ? 1.f : 0.f;
      float vx0 = (x0i >= 0 && x0i < HW) ? 1.f : 0.f;
      float vx1 = (x1 >= 0 && x1 < HW) ? 1.f : 0.f;
      int y0c = min(max(y0, 0), HW - 1), y1c = min(max(y1, 0), HW - 1);
      int x0c = min(max(x0i, 0), HW - 1), x1c = min(max(x1, 0), HW - 1);
      __half2 h00 = __float2half2_rn((1.f - wy) * (1.f - wx) * vy0 * vx0);
      __half2 h01 = __float2half2_rn((1.f - wy) * wx * vy0 * vx1);
      __half2 h10 = __float2half2_rn(wy * (1.f - wx) * vy1 * vx0);
      __half2 h11 = __float2half2_rn(wy * wx * vy1 * vx1);

      const int wy0 = y0c - by + 2, wy1 = y1c - by + 2;
      const int wx0 = x0c - bx + 2, wx1 = x1c - bx + 2;
      const bool inw = ((unsigned)wy0 < 20u) && ((unsigned)wy1 < 20u) &&
                       ((unsigned)wx0 < 20u) && ((unsigned)wx1 < 20u);
      uint4 c00[2], c01[2], c10[2], c11[2];
      if (inw) {
        const unsigned short* q00 = win + (wy0 * 20 + wx0) * 72 + lg * 8;
        const unsigned short* q01 = win + (wy0 * 20 + wx1) * 72 + lg * 8;
        const unsigned short* q10 = win + (wy1 * 20 + wx0) * 72 + lg * 8;
        const unsigned short* q11 = win + (wy1 * 20 + wx1) * 72 + lg * 8;
#pragma unroll
        for (int ks = 0; ks < 2; ++ks) {
          c00[ks] = *(const uint4*)(q00 + ks * 32);
          c01[ks] = *(const uint4*)(q01 + ks * 32);
          c10[ks] = *(const uint4*)(q10 + ks * 32);
          c11[ks] = *(const uint4*)(q11 + ks * 32);
        }
      } else {
        const unsigned short* p00 = tb + (y0c * HW + x0c) * 64 + lg * 8;
        const unsigned short* p01 = tb + (y0c * HW + x1c) * 64 + lg * 8;
        const unsigned short* p10 = tb + (y1c * HW + x0c) * 64 + lg * 8;
        const unsigned short* p11 = tb + (y1c * HW + x1c) * 64 + lg * 8;
#pragma unroll
        for (int ks = 0; ks < 2; ++ks) {
          c00[ks] = *(const uint4*)(p00 + ks * 32);
          c01[ks] = *(const uint4*)(p01 + ks * 32);
          c10[ks] = *(const uint4*)(p10 + ks * 32);
          c11[ks] = *(const uint4*)(p11 + ks * 32);
        }
      }
#pragma unroll
      for (int ks = 0; ks < 2; ++ks) {
        uint4 r = blend4(c00[ks], c01[ks], c10[ks], c11[ks], h00, h01, h10, h11);
        af[q][ks] = *(const f16x8*)&r;
      }
    }

#pragma unroll
    for (int ks = 0; ks < 2; ++ks) {
      const int kb = kk * 8 + ks * 4 + lg;
      f16x8 bw[4];
#pragma unroll
      for (int nf = 0; nf < 4; ++nf)
        bw[nf] = *(const f16x8*)(wdp + (kb * 64 + nf * 16 + l15) * 8);
#pragma unroll
      for (int q = 0; q < 2; ++q)
#pragma unroll
        for (int nf = 0; nf < 4; ++nf)
          acc[q][nf] = __builtin_amdgcn_mfma_f32_16x16x32_f16(af[q][ks], bw[nf], acc[q][nf], 0, 0, 0);
    }
  }

  const int px0 = bx + lg * 4;
#pragma unroll
  for (int q = 0; q < 2; ++q) {
    const int py = by + w * 2 + q;
#pragma unroll
    for (int nf = 0; nf < 4; ++nf) {
      const int oc = nf * 16 + l15;
      float4 o;
      o.x = acc[q][nf][0];
      o.y = acc[q][nf][1];
      o.z = acc[q][nf][2];
      o.w = acc[q][nf][3];
      *(float4*)(out + (size_t)(b * 64 + oc) * PLANE + py * HW + px0) = o;
    }
  }
}

extern "C" void kernel_launch(void* const* d_in, const int* in_sizes, int n_in,
                              void* d_out, int out_size, void* d_ws, size_t ws_size,
                              hipStream_t stream) {
  const float* ref = (const float*)d_in[0];
  const float* tgt = (const float*)d_in[1];
  const float* w1  = (const float*)d_in[2];
  const float* b1  = (const float*)d_in[3];
  const float* w2  = (const float*)d_in[4];
  const float* b2  = (const float*)d_in[5];
  const float* wd  = (const float*)d_in[6];

  // xref (fp16 NHWC, 16.8 MB) lives in d_out: dead before deform overwrites d_out.
  unsigned short* xref = (unsigned short*)d_out;
  float* out = (float*)d_out;

  char* ws = (char*)d_ws;
  unsigned short* xtgt  = (unsigned short*)ws;                   // 16777216 B
  unsigned short* hmid  = (unsigned short*)(ws + 16777216);      // 16777216 B
  float*          offsG = (float*)(ws + 33554432);               // 9437184 B
  unsigned short* w1p   = (unsigned short*)(ws + 42991616);      // 147456 B
  unsigned short* w2p   = (unsigned short*)(ws + 43139072);      // 36864 B
  unsigned short* wdp   = (unsigned short*)(ws + 43175936);      // 73728 B; end = 43249664

  pack_all_kernel<<<504, 256, 0, stream>>>(w1, w2, wd, w1p, w2p, wdp);

  to_nhwc_kernel<<<dim3(4, 128, 8), 256, 0, stream>>>(ref, tgt, xref, xtgt);

  conv1_mfma_kernel<<<512, 512, 0, stream>>>(xref, xtgt, w1p, b1, hmid);
  conv2_mfma_kernel<<<512, 512, 0, stream>>>(hmid, w2p, b2, offsG);
  deform_kernel<<<512, 512, 0, stream>>>(xtgt, offsG, wdp, out);
}